// Round 2
// baseline (18263.995 us; speedup 1.0000x reference)
//
#include <hip/hip_runtime.h>
#include <hip/hip_bf16.h>

// LSTM decoder: L=2, B=64, T=512, H=IN=512, gates G=2048 (i,f,g,o).
// Round 2: ws shrunk to ~17.3MB (round-1 overflow corrupted harness pristine
// buffers -> post-timing divergence). Per-timestep launches, layer-pipelined
// (layer0@t, layer1@t-1). MFMA 16x16x32 bf16, split-precision (hi+lo) weights
// and hidden state. One block per (j-block, layer): W read once per dispatch.

#define TT 512
#define HH 512
#define BB 64

using short8 = __attribute__((ext_vector_type(8))) short;
using f32x4  = __attribute__((ext_vector_type(4))) float;

__device__ __forceinline__ short f2bf(float f) {
  unsigned u = __float_as_uint(f);
  u = (u + 0x7fffu + ((u >> 16) & 1u)) >> 16;  // RNE
  return (short)u;
}
__device__ __forceinline__ float bf2f(short s) {
  return __uint_as_float(((unsigned)(unsigned short)s) << 16);
}
__device__ __forceinline__ float sigf(float x) { return 1.f / (1.f + __expf(-x)); }
__device__ __forceinline__ float tanh_(float x) { return 1.f - 2.f / (__expf(2.f * x) + 1.f); }

// ---- weight conversion: fp32 [l][2048][512] (ih,hh) -> fragment-packed bf16
// hi+lo. Fragment layout: [l][s][rowgrp=R>>4][chunk=K>>5][lane][e] with
// lane = (R&15) + 16*((K>>3)&3), e = K&7. A wave's chunk load = contiguous 1KB.
__global__ __launch_bounds__(256) void conv_w(const float* __restrict__ Wih,
                                              const float* __restrict__ Whh,
                                              short* __restrict__ whi,
                                              short* __restrict__ wlo) {
  int i = blockIdx.x * 256 + threadIdx.x;  // 0..524287 : (l,s,R,K8)
  int l = i >> 18;
  int rem = i & 262143;
  int s = rem >> 17;
  int rem2 = rem & 131071;
  int R = rem2 >> 6;
  int K8 = rem2 & 63;
  const float* src = (s == 0 ? Wih : Whh) + ((size_t)(l * 2048 + R)) * 512 + K8 * 8;
  size_t off = ((size_t)(((l * 2 + s) * 128 + (R >> 4)) * 16 + (K8 >> 2))) * 512 +
               ((R & 15) + 16 * (K8 & 3)) * 8;
  float4 v0 = *(const float4*)(src);
  float4 v1 = *(const float4*)(src + 4);
  float vv[8] = {v0.x, v0.y, v0.z, v0.w, v1.x, v1.y, v1.z, v1.w};
  short8 h, lo;
#pragma unroll
  for (int e = 0; e < 8; ++e) {
    short hi = f2bf(vv[e]);
    h[e] = hi;
    lo[e] = f2bf(vv[e] - bf2f(hi));
  }
  *(short8*)(whi + off) = h;
  *(short8*)(wlo + off) = lo;
}

__global__ __launch_bounds__(256) void init_state(const float* __restrict__ h0,
                                                  const float* __restrict__ c0,
                                                  short* __restrict__ hhi,
                                                  short* __restrict__ hlo,
                                                  float* __restrict__ hfp,
                                                  float* __restrict__ cst) {
  int i = blockIdx.x * 256 + threadIdx.x;  // 0..65535 ([l][b][j] flat)
  int l = i >> 15, bh = i & 32767;
  float h = h0[i];
  short hi = f2bf(h);
  int o = (l * 2 + 0) * 32768 + bh;  // parity 0
  hhi[o] = hi;
  hlo[o] = f2bf(h - bf2f(hi));
  hfp[o] = h;
  cst[i] = c0[i];
}

__global__ __launch_bounds__(256) void finalize(const float* __restrict__ hfp,
                                                const float* __restrict__ cst,
                                                float* __restrict__ out) {
  int i = blockIdx.x * 256 + threadIdx.x;  // 0..131071
  if (i < 65536) {
    int l = i >> 15, bh = i & 32767;
    out[16777216 + i] = hfp[(l * 2 + 0) * 32768 + bh];  // final parity = 0
  } else {
    int j = i - 65536;
    out[16777216 + 65536 + j] = cst[j];
  }
}

// ---- main step kernel ---------------------------------------------------
// grid: (32 j-blocks, 2 layers); block: 512 threads = 8 waves.
// wave w: gate g = w>>1, batch-half hb = w&1 (2 MFMA C-tiles of 16 batches).
__global__ __launch_bounds__(512) void lstm_step(
    const float* __restrict__ x, const short* __restrict__ whi,
    const short* __restrict__ wlo, const float* __restrict__ bih,
    const float* __restrict__ bhh, short* __restrict__ hhi,
    short* __restrict__ hlo, float* __restrict__ hfp, float* __restrict__ cst,
    float* __restrict__ out, int t) {
  const int layer = blockIdx.y;
  const int tl = layer ? (t - 1) : t;
  if (tl < 0 || tl >= TT) return;
  const int jb = blockIdx.x;           // j0 = jb*16
  const int tid = threadIdx.x;
  const int w = tid >> 6;
  const int g = w >> 1;                // gate (i,f,g,o)
  const int hb = w & 1;                // batch half
  const int lane = tid & 63;
  const int m = lane & 15;
  const int koq = lane >> 4;           // 0..3
  const int ko = koq << 3;
  const int pin = tl & 1, pout = pin ^ 1;
  const int B0 = hb << 5;
  const int b0t = B0 + m;              // tile0 batch row
  const int b1t = B0 + 16 + m;         // tile1 batch row

  // W fragment pointers: within [l][s] region (1,048,576 shorts):
  // addr = rg*8192 + c*512 + lane*8, rg = g*32 + jb.
  const int rg = (g << 5) + jb;
  const size_t wb = (size_t)rg * 8192 + lane * 8;
  const short* pih_h = whi + (size_t)(layer * 2 + 0) * 1048576 + wb;
  const short* pih_l = wlo + (size_t)(layer * 2 + 0) * 1048576 + wb;
  const short* phh_h = whi + (size_t)(layer * 2 + 1) * 1048576 + wb;
  const short* phh_l = wlo + (size_t)(layer * 2 + 1) * 1048576 + wb;

  // recurrent input rows (plain [slot][b][k] layout)
  const int slotR = layer * 2 + pin;
  const short* a2h0 = hhi + ((slotR * BB + b0t) * 512) + ko;
  const short* a2l0 = hlo + ((slotR * BB + b0t) * 512) + ko;
  const short* a2h1 = hhi + ((slotR * BB + b1t) * 512) + ko;
  const short* a2l1 = hlo + ((slotR * BB + b1t) * 512) + ko;

  f32x4 acc0 = {0.f, 0.f, 0.f, 0.f};
  f32x4 acc1 = {0.f, 0.f, 0.f, 0.f};

  if (layer == 0) {
    // phase ih: x fp32 -> bf16 on the fly (single-bf16 x, as validated)
    const float* xa0 = x + ((size_t)b0t * TT + tl) * 512 + ko;
    const float* xa1 = x + ((size_t)b1t * TT + tl) * 512 + ko;
#pragma unroll 4
    for (int c = 0; c < 16; ++c) {
      short8 wh = *(const short8*)(pih_h + c * 512);
      short8 wl = *(const short8*)(pih_l + c * 512);
      float4 u0 = *(const float4*)(xa0 + c * 32);
      float4 u1 = *(const float4*)(xa0 + c * 32 + 4);
      float4 v0 = *(const float4*)(xa1 + c * 32);
      float4 v1 = *(const float4*)(xa1 + c * 32 + 4);
      short8 a0, a1;
      a0[0] = f2bf(u0.x); a0[1] = f2bf(u0.y); a0[2] = f2bf(u0.z); a0[3] = f2bf(u0.w);
      a0[4] = f2bf(u1.x); a0[5] = f2bf(u1.y); a0[6] = f2bf(u1.z); a0[7] = f2bf(u1.w);
      a1[0] = f2bf(v0.x); a1[1] = f2bf(v0.y); a1[2] = f2bf(v0.z); a1[3] = f2bf(v0.w);
      a1[4] = f2bf(v1.x); a1[5] = f2bf(v1.y); a1[6] = f2bf(v1.z); a1[7] = f2bf(v1.w);
      acc0 = __builtin_amdgcn_mfma_f32_16x16x32_bf16(a0, wh, acc0, 0, 0, 0);
      acc0 = __builtin_amdgcn_mfma_f32_16x16x32_bf16(a0, wl, acc0, 0, 0, 0);
      acc1 = __builtin_amdgcn_mfma_f32_16x16x32_bf16(a1, wh, acc1, 0, 0, 0);
      acc1 = __builtin_amdgcn_mfma_f32_16x16x32_bf16(a1, wl, acc1, 0, 0, 0);
    }
  } else {
    // phase ih: input = layer0 output at time tl (hi+lo), parity (tl+1)&1 = t&1
    const int slotA = 0 * 2 + (t & 1);
    const short* a1h0 = hhi + ((slotA * BB + b0t) * 512) + ko;
    const short* a1l0 = hlo + ((slotA * BB + b0t) * 512) + ko;
    const short* a1h1 = hhi + ((slotA * BB + b1t) * 512) + ko;
    const short* a1l1 = hlo + ((slotA * BB + b1t) * 512) + ko;
#pragma unroll 4
    for (int c = 0; c < 16; ++c) {
      short8 wh = *(const short8*)(pih_h + c * 512);
      short8 wl = *(const short8*)(pih_l + c * 512);
      short8 a0 = *(const short8*)(a1h0 + c * 32);
      short8 l0 = *(const short8*)(a1l0 + c * 32);
      short8 a1 = *(const short8*)(a1h1 + c * 32);
      short8 l1 = *(const short8*)(a1l1 + c * 32);
      acc0 = __builtin_amdgcn_mfma_f32_16x16x32_bf16(a0, wh, acc0, 0, 0, 0);
      acc0 = __builtin_amdgcn_mfma_f32_16x16x32_bf16(a0, wl, acc0, 0, 0, 0);
      acc0 = __builtin_amdgcn_mfma_f32_16x16x32_bf16(l0, wh, acc0, 0, 0, 0);
      acc1 = __builtin_amdgcn_mfma_f32_16x16x32_bf16(a1, wh, acc1, 0, 0, 0);
      acc1 = __builtin_amdgcn_mfma_f32_16x16x32_bf16(a1, wl, acc1, 0, 0, 0);
      acc1 = __builtin_amdgcn_mfma_f32_16x16x32_bf16(l1, wh, acc1, 0, 0, 0);
    }
  }

  // phase hh: recurrent (hi+lo both operands, 3 terms)
#pragma unroll 4
  for (int c = 0; c < 16; ++c) {
    short8 wh = *(const short8*)(phh_h + c * 512);
    short8 wl = *(const short8*)(phh_l + c * 512);
    short8 a0 = *(const short8*)(a2h0 + c * 32);
    short8 l0 = *(const short8*)(a2l0 + c * 32);
    short8 a1 = *(const short8*)(a2h1 + c * 32);
    short8 l1 = *(const short8*)(a2l1 + c * 32);
    acc0 = __builtin_amdgcn_mfma_f32_16x16x32_bf16(a0, wh, acc0, 0, 0, 0);
    acc0 = __builtin_amdgcn_mfma_f32_16x16x32_bf16(a0, wl, acc0, 0, 0, 0);
    acc0 = __builtin_amdgcn_mfma_f32_16x16x32_bf16(l0, wh, acc0, 0, 0, 0);
    acc1 = __builtin_amdgcn_mfma_f32_16x16x32_bf16(a1, wh, acc1, 0, 0, 0);
    acc1 = __builtin_amdgcn_mfma_f32_16x16x32_bf16(a1, wl, acc1, 0, 0, 0);
    acc1 = __builtin_amdgcn_mfma_f32_16x16x32_bf16(l1, wh, acc1, 0, 0, 0);
  }

  // epilogue: C/D layout col = lane&15 (=j), row = koq*4 + reg (=batch in tile)
  const int grow = (g << 9) + (jb << 4) + m;
  const float biasv = bih[layer * 2048 + grow] + bhh[layer * 2048 + grow];
  __shared__ float sG[4][64][17];
  const int br = koq << 2;
#pragma unroll
  for (int r = 0; r < 4; ++r) {
    sG[g][B0 + br + r][m] = acc0[r] + biasv;
    sG[g][B0 + 16 + br + r][m] = acc1[r] + biasv;
  }
  __syncthreads();

#pragma unroll
  for (int rep = 0; rep < 2; ++rep) {
    const int idx = tid + rep * 512;       // 0..1023 over [64 b][16 j]
    const int bl = idx >> 4, jl = idx & 15;
    const float iv = sG[0][bl][jl];
    const float fv = sG[1][bl][jl];
    const float gv = sG[2][bl][jl];
    const float ov = sG[3][bl][jl];
    const int jg = (jb << 4) + jl;
    const int sidx = (layer * BB + bl) * 512 + jg;
    const float c = cst[sidx];
    const float cn = sigf(fv) * c + sigf(iv) * tanh_(gv);
    const float hn = sigf(ov) * tanh_(cn);
    cst[sidx] = cn;
    const int ho = ((layer * 2 + pout) * BB + bl) * 512 + jg;
    const short hbv = f2bf(hn);
    hhi[ho] = hbv;
    hlo[ho] = f2bf(hn - bf2f(hbv));
    hfp[ho] = hn;
    if (layer) out[((size_t)bl * TT + tl) * 512 + jg] = hn;
  }
}

// ---- host ---------------------------------------------------------------

extern "C" void kernel_launch(void* const* d_in, const int* in_sizes, int n_in,
                              void* d_out, int out_size, void* d_ws,
                              size_t ws_size, hipStream_t stream) {
  const float* x = (const float*)d_in[0];
  const float* h0 = (const float*)d_in[1];
  const float* c0 = (const float*)d_in[2];
  const float* Wih = (const float*)d_in[3];
  const float* Whh = (const float*)d_in[4];
  const float* bih = (const float*)d_in[5];
  const float* bhh = (const float*)d_in[6];
  float* out = (float*)d_out;

  char* ws = (char*)d_ws;
  short* whi = (short*)(ws + 0);          // 8 MB   W hi (fragment-packed)
  short* wlo = (short*)(ws + 8388608);    // 8 MB   W lo
  short* hhi = (short*)(ws + 16777216);   // 256 KB h hi  [l][p][b][j]
  short* hlo = (short*)(ws + 17039360);   // 256 KB h lo
  float* hfp = (float*)(ws + 17301504);   // 512 KB h fp32 shadow
  float* cst = (float*)(ws + 17825792);   // 256 KB c fp32
  // total ws use: 18,088,064 B ~= 17.3 MB

  conv_w<<<2048, 256, 0, stream>>>(Wih, Whh, whi, wlo);
  init_state<<<256, 256, 0, stream>>>(h0, c0, hhi, hlo, hfp, cst);

  dim3 grid(32, 2);
  for (int t = 0; t <= TT; ++t) {
    lstm_step<<<grid, 512, 0, stream>>>(x, whi, wlo, bih, bhh, hhi, hlo, hfp,
                                        cst, out, t);
  }
  finalize<<<512, 256, 0, stream>>>(hfp, cst, out);
}

// Round 3
// 14706.244 us; speedup vs baseline: 1.2419x; 1.2419x over previous
//
#include <hip/hip_runtime.h>
#include <hip/hip_bf16.h>
#include <hip/hip_cooperative_groups.h>

// LSTM decoder: L=2, B=64, T=512, H=IN=512, gates G=2048 (i,f,g,o).
// Round 3: persistent cooperative kernel. 128 blocks (64/layer), each owns
// 8 hidden units x 4 gates (32 gate-rows); W slice (96KB) resident in LDS for
// all 512 timesteps; 513 grid.sync()s replace 513 kernel launches.
// K-split-4 across the 4 waves (W read once per step), LDS partial-reduce
// fused into the cell update. c and final-h in registers. x pre-converted to
// bf16 into d_out rows (row (b,t) read at phase t, overwritten at phase t+1).
// Numerics: ih = bf16 x bf16 (single); hh = hi+lo W x hi+lo h (3 MFMA, the
// round-2-validated recurrent split); bias/c/activations fp32.

#define TT 512
namespace cg = cooperative_groups;

using short8 = __attribute__((ext_vector_type(8))) short;
using f32x4  = __attribute__((ext_vector_type(4))) float;

__device__ __forceinline__ short f2bf(float f) {
  unsigned u = __float_as_uint(f);
  u = (u + 0x7fffu + ((u >> 16) & 1u)) >> 16;  // RNE
  return (short)u;
}
__device__ __forceinline__ float bf2f(short s) {
  return __uint_as_float(((unsigned)(unsigned short)s) << 16);
}
__device__ __forceinline__ float sigf(float x) { return 1.f / (1.f + __expf(-x)); }
__device__ __forceinline__ float tanh_(float x) { return 1.f - 2.f / (__expf(2.f * x) + 1.f); }

// ---- x fp32 [64][512][512] -> bf16 stored in first half of each out row ----
__global__ __launch_bounds__(256) void conv_x(const float* __restrict__ x,
                                              short* __restrict__ xo) {
  size_t g = (size_t)blockIdx.x * 256 + threadIdx.x;  // 2,097,152 total
  size_t i = g * 8;
  float4 v0 = *(const float4*)(x + i);
  float4 v1 = *(const float4*)(x + i + 4);
  short8 r;
  r[0] = f2bf(v0.x); r[1] = f2bf(v0.y); r[2] = f2bf(v0.z); r[3] = f2bf(v0.w);
  r[4] = f2bf(v1.x); r[5] = f2bf(v1.y); r[6] = f2bf(v1.z); r[7] = f2bf(v1.w);
  *(short8*)(xo + (i >> 9) * 1024 + (i & 511)) = r;
}

// ---- W pack: per-block contiguous LDS image (49152 shorts per (l,j8)) ----
// image: [0,16384): ih-hi  seg=(bt*16+c) in [0,32), offset seg*512+lane*8
//        [16384,49152): hh  seg=((bt*16+c)*2+hl) in [0,64)
// fragment: r=lane&15 -> gate g=r>>2, jj=r&3; R=g*512+j8*8+bt*4+jj;
//           k=c*32+(lane>>4)*8+e
__global__ __launch_bounds__(256) void conv_w(const float* __restrict__ Wih,
                                              const float* __restrict__ Whh,
                                              short* __restrict__ wp) {
  int g = blockIdx.x * 256 + threadIdx.x;  // 0..786431
  int l = g / 393216;
  int rem = g % 393216;
  int j8 = rem / 6144;
  int q8 = rem % 6144;
  int s, hl, bt, c, lane;
  if (q8 < 2048) {
    s = 0; hl = 0;
    int seg = q8 >> 6; bt = seg >> 4; c = seg & 15; lane = q8 & 63;
  } else {
    int q = q8 - 2048;
    s = 1;
    int seg = q >> 6; bt = seg >> 5; c = (seg >> 1) & 15; hl = seg & 1;
    lane = q & 63;
  }
  int r = lane & 15;
  int gg = r >> 2, jj = r & 3;
  int R = gg * 512 + j8 * 8 + bt * 4 + jj;
  int k = c * 32 + (lane >> 4) * 8;
  const float* src = (s ? Whh : Wih) + ((size_t)(l * 2048 + R)) * 512 + k;
  short8 o;
#pragma unroll
  for (int e = 0; e < 8; ++e) {
    float v = src[e];
    short hi = f2bf(v);
    o[e] = hl ? f2bf(v - bf2f(hi)) : hi;
  }
  *(short8*)(wp + (size_t)g * 8) = o;
}

// ---- h0 -> parity-0 hi/lo slots ----
__global__ __launch_bounds__(256) void init_state(const float* __restrict__ h0,
                                                  short* __restrict__ hhi,
                                                  short* __restrict__ hlo) {
  int i = blockIdx.x * 256 + threadIdx.x;  // 0..65535 [l][b][j]
  int l = i >> 15, bj = i & 32767;
  float h = h0[i];
  short hi = f2bf(h);
  int o = (l * 2) * 32768 + bj;
  hhi[o] = hi;
  hlo[o] = f2bf(h - bf2f(hi));
}

// ---- persistent LSTM ----------------------------------------------------
// grid 128 = [layer(2)][j8(64)]; block 256 = 4 waves; dynamic LDS 132096B:
//   [0,98304): W image (96KB); [98304,...): float sG[4][32][66] partials.
__global__ __launch_bounds__(256, 1) void lstm_persist(
    const short* __restrict__ wp, const float* __restrict__ c0,
    const float* __restrict__ bih, const float* __restrict__ bhh,
    short* __restrict__ hhi, short* __restrict__ hlo,
    float* __restrict__ out) {
  extern __shared__ char smem[];
  short* lw = (short*)smem;                 // 49152 shorts
  float* sG = (float*)(smem + 98304);       // [w][s][b] stride 66

  const int tid = threadIdx.x;
  const int layer = blockIdx.x >> 6;
  const int j8 = blockIdx.x & 63;
  const int j0 = j8 << 3;
  const int wv = tid >> 6;
  const int lane = tid & 63;
  const int m = lane & 15;
  const int ko = (lane >> 4) << 3;

  {  // W slice -> LDS (one-time)
    const short* src = wp + (size_t)(layer * 64 + j8) * 49152;
    for (int i = tid; i < 6144; i += 256)
      *(short8*)(lw + i * 8) = *(const short8*)(src + i * 8);
  }

  // per-thread cell state: pair p -> flat = p*256+tid: jj8 = flat>>6, b = flat&63
  float creg[2], hf[2];
  float bsum[2][4];
  int pj[2], pb[2];
#pragma unroll
  for (int p = 0; p < 2; ++p) {
    int flat = p * 256 + tid;
    int jj8 = flat >> 6, b = flat & 63;
    int j = j0 + jj8;
    pj[p] = jj8; pb[p] = b;
    creg[p] = c0[layer * 32768 + b * 512 + j];
    hf[p] = 0.f;
#pragma unroll
    for (int g = 0; g < 4; ++g)
      bsum[p][g] = bih[layer * 2048 + g * 512 + j] + bhh[layer * 2048 + g * 512 + j];
  }
  __syncthreads();

  cg::grid_group gridg = cg::this_grid();
  const short* xo = (const short*)out;
  const int cbase = wv << 2;  // this wave's 4 K-chunks (K-split)

  for (int t = 0; t <= TT; ++t) {
    const int tl = layer ? (t - 1) : t;
    if (tl >= 0 && tl < TT) {
      const int pin = tl & 1, pout = pin ^ 1;
      f32x4 acc[2][4] = {};

      // ---- s=0: ih (single bf16) ----
      if (layer == 0) {
#pragma unroll
        for (int cc = 0; cc < 4; ++cc) {
          const int c = cbase + cc;
          const int k = c * 32 + ko;
          short8 b0 = *(const short8*)(lw + (c)*512 + lane * 8);
          short8 b1 = *(const short8*)(lw + (16 + c) * 512 + lane * 8);
#pragma unroll
          for (int at = 0; at < 4; ++at) {
            const int br = at * 16 + m;
            short8 a = *(const short8*)(xo + ((size_t)br * 512 + tl) * 1024 + k);
            acc[0][at] = __builtin_amdgcn_mfma_f32_16x16x32_bf16(a, b0, acc[0][at], 0, 0, 0);
            acc[1][at] = __builtin_amdgcn_mfma_f32_16x16x32_bf16(a, b1, acc[1][at], 0, 0, 0);
          }
        }
      } else {
        const short* ah = hhi + ((t & 1)) * 32768;  // layer0 out parity = (tl+1)&1
#pragma unroll
        for (int cc = 0; cc < 4; ++cc) {
          const int c = cbase + cc;
          const int k = c * 32 + ko;
          short8 b0 = *(const short8*)(lw + (c)*512 + lane * 8);
          short8 b1 = *(const short8*)(lw + (16 + c) * 512 + lane * 8);
#pragma unroll
          for (int at = 0; at < 4; ++at) {
            const int br = at * 16 + m;
            short8 a = *(const short8*)(ah + br * 512 + k);
            acc[0][at] = __builtin_amdgcn_mfma_f32_16x16x32_bf16(a, b0, acc[0][at], 0, 0, 0);
            acc[1][at] = __builtin_amdgcn_mfma_f32_16x16x32_bf16(a, b1, acc[1][at], 0, 0, 0);
          }
        }
      }

      // ---- s=1: hh (hi+lo W, hi+lo h: 3 MFMA) ----
      {
        const int slotR = layer * 2 + pin;
        const short* rh = hhi + slotR * 32768;
        const short* rl = hlo + slotR * 32768;
#pragma unroll
        for (int cc = 0; cc < 4; ++cc) {
          const int c = cbase + cc;
          const int k = c * 32 + ko;
          short8 bh0 = *(const short8*)(lw + 16384 + ((c)*2 + 0) * 512 + lane * 8);
          short8 bl0 = *(const short8*)(lw + 16384 + ((c)*2 + 1) * 512 + lane * 8);
          short8 bh1 = *(const short8*)(lw + 16384 + ((16 + c) * 2 + 0) * 512 + lane * 8);
          short8 bl1 = *(const short8*)(lw + 16384 + ((16 + c) * 2 + 1) * 512 + lane * 8);
#pragma unroll
          for (int at = 0; at < 4; ++at) {
            const int br = at * 16 + m;
            short8 a = *(const short8*)(rh + br * 512 + k);
            short8 al = *(const short8*)(rl + br * 512 + k);
            acc[0][at] = __builtin_amdgcn_mfma_f32_16x16x32_bf16(a, bh0, acc[0][at], 0, 0, 0);
            acc[0][at] = __builtin_amdgcn_mfma_f32_16x16x32_bf16(a, bl0, acc[0][at], 0, 0, 0);
            acc[0][at] = __builtin_amdgcn_mfma_f32_16x16x32_bf16(al, bh0, acc[0][at], 0, 0, 0);
            acc[1][at] = __builtin_amdgcn_mfma_f32_16x16x32_bf16(a, bh1, acc[1][at], 0, 0, 0);
            acc[1][at] = __builtin_amdgcn_mfma_f32_16x16x32_bf16(a, bl1, acc[1][at], 0, 0, 0);
            acc[1][at] = __builtin_amdgcn_mfma_f32_16x16x32_bf16(al, bh1, acc[1][at], 0, 0, 0);
          }
        }
      }

      // ---- partials -> sG ----
#pragma unroll
      for (int bt = 0; bt < 2; ++bt)
#pragma unroll
        for (int at = 0; at < 4; ++at) {
          const int s = bt * 16 + m;
          const int bb = at * 16 + ((lane >> 4) << 2);
#pragma unroll
          for (int r = 0; r < 4; ++r)
            sG[(wv * 32 + s) * 66 + bb + r] = acc[bt][at][r];
        }
      __syncthreads();

      // ---- reduce + cell update (2 pairs/thread) ----
#pragma unroll
      for (int p = 0; p < 2; ++p) {
        const int jj8 = pj[p], b = pb[p];
        const int bt = jj8 >> 2, jj = jj8 & 3;
        float gv[4];
#pragma unroll
        for (int g = 0; g < 4; ++g) {
          const int s = bt * 16 + g * 4 + jj;
          gv[g] = sG[(0 * 32 + s) * 66 + b] + sG[(1 * 32 + s) * 66 + b] +
                  sG[(2 * 32 + s) * 66 + b] + sG[(3 * 32 + s) * 66 + b] +
                  bsum[p][g];
        }
        const float cn = sigf(gv[1]) * creg[p] + sigf(gv[0]) * tanh_(gv[2]);
        const float hn = sigf(gv[3]) * tanh_(cn);
        creg[p] = cn;
        hf[p] = hn;
        const int j = j0 + jj8;
        const int ho = (layer * 2 + pout) * 32768 + b * 512 + j;
        const short hb = f2bf(hn);
        hhi[ho] = hb;
        hlo[ho] = f2bf(hn - bf2f(hb));
        if (layer) out[((size_t)b * 512 + tl) * 512 + j] = hn;
      }
    }
    gridg.sync();
  }

  // finals from registers
#pragma unroll
  for (int p = 0; p < 2; ++p) {
    const int b = pb[p], j = j0 + pj[p];
    out[16777216 + layer * 32768 + b * 512 + j] = hf[p];
    out[16777216 + 65536 + layer * 32768 + b * 512 + j] = creg[p];
  }
}

// ---- host ---------------------------------------------------------------

extern "C" void kernel_launch(void* const* d_in, const int* in_sizes, int n_in,
                              void* d_out, int out_size, void* d_ws,
                              size_t ws_size, hipStream_t stream) {
  const float* x = (const float*)d_in[0];
  const float* h0 = (const float*)d_in[1];
  const float* c0 = (const float*)d_in[2];
  const float* Wih = (const float*)d_in[3];
  const float* Whh = (const float*)d_in[4];
  const float* bih = (const float*)d_in[5];
  const float* bhh = (const float*)d_in[6];
  float* out = (float*)d_out;

  char* ws = (char*)d_ws;
  short* wp = (short*)(ws + 0);            // 12 MB  fragment-packed W images
  short* hhi = (short*)(ws + 12582912);    // 256 KB h hi [4 slots][64][512]
  short* hlo = (short*)(ws + 12845056);    // 256 KB h lo
  // total ws use: 13,107,200 B ~= 12.5 MB (round-2-proven budget)

  static bool attr_done = false;
  hipFuncSetAttribute(reinterpret_cast<const void*>(lstm_persist),
                      hipFuncAttributeMaxDynamicSharedMemorySize, 132096);
  (void)attr_done;

  conv_x<<<8192, 256, 0, stream>>>(x, (short*)out);
  conv_w<<<3072, 256, 0, stream>>>(Wih, Whh, wp);
  init_state<<<256, 256, 0, stream>>>(h0, hhi, hlo);

  void* args[] = {(void*)&wp, (void*)&c0, (void*)&bih, (void*)&bhh,
                  (void*)&hhi, (void*)&hlo, (void*)&out};
  hipLaunchCooperativeKernel(reinterpret_cast<void*>(lstm_persist), dim3(128),
                             dim3(256), args, 132096, stream);
}

// Round 4
// 10296.568 us; speedup vs baseline: 1.7738x; 1.4283x over previous
//
#include <hip/hip_runtime.h>
#include <hip/hip_bf16.h>

// LSTM decoder: L=2, B=64, T=512, H=IN=512, gates G=2048 (i,f,g,o).
// Round 4: persistent kernel, custom lightweight grid barrier (monotonic
// counter + relaxed agent polling), blocked h layout [slot][k8][b][8] so every
// block owns full 128B lines (kills cross-XCD partial-line RMW) and A-frag
// loads are coalesced. 128 blocks x 512 thr (8 waves: K-quarter x batch-half).
// W slice (96KB) in LDS. Numerics identical to validated round 2/3:
// ih = single bf16 (x fp32->bf16 on the fly), hh = hi+lo W x hi+lo h.

#define TT 512

using short8 = __attribute__((ext_vector_type(8))) short;
using f32x4  = __attribute__((ext_vector_type(4))) float;

__device__ __forceinline__ short f2bf(float f) {
  unsigned u = __float_as_uint(f);
  u = (u + 0x7fffu + ((u >> 16) & 1u)) >> 16;  // RNE
  return (short)u;
}
__device__ __forceinline__ float bf2f(short s) {
  return __uint_as_float(((unsigned)(unsigned short)s) << 16);
}
__device__ __forceinline__ float sigf(float x) { return 1.f / (1.f + __expf(-x)); }
__device__ __forceinline__ float tanh_(float x) { return 1.f - 2.f / (__expf(2.f * x) + 1.f); }

// ---- W pack: per-block contiguous LDS image (49152 shorts per (l,j8)) ----
// image: [0,16384): ih-hi  seg=(bt*16+c), offset seg*512+lane*8
//        [16384,49152): hh  seg=((bt*16+c)*2+hl)
// fragment: r=lane&15 -> gate g=r>>2, jj=r&3; R=g*512+j8*8+bt*4+jj;
//           k=c*32+(lane>>4)*8+e
__global__ __launch_bounds__(256) void conv_w(const float* __restrict__ Wih,
                                              const float* __restrict__ Whh,
                                              short* __restrict__ wp) {
  int g = blockIdx.x * 256 + threadIdx.x;  // 0..786431
  int l = g / 393216;
  int rem = g % 393216;
  int j8 = rem / 6144;
  int q8 = rem % 6144;
  int s, hl, bt, c, lane;
  if (q8 < 2048) {
    s = 0; hl = 0;
    int seg = q8 >> 6; bt = seg >> 4; c = seg & 15; lane = q8 & 63;
  } else {
    int q = q8 - 2048;
    s = 1;
    int seg = q >> 6; bt = seg >> 5; c = (seg >> 1) & 15; hl = seg & 1;
    lane = q & 63;
  }
  int r = lane & 15;
  int gg = r >> 2, jj = r & 3;
  int R = gg * 512 + j8 * 8 + bt * 4 + jj;
  int k = c * 32 + (lane >> 4) * 8;
  const float* src = (s ? Whh : Wih) + ((size_t)(l * 2048 + R)) * 512 + k;
  short8 o;
#pragma unroll
  for (int e = 0; e < 8; ++e) {
    float v = src[e];
    short hi = f2bf(v);
    o[e] = hl ? f2bf(v - bf2f(hi)) : hi;
  }
  *(short8*)(wp + (size_t)g * 8) = o;
}

// ---- h0 -> parity-0 slots in blocked layout [slot][k8=64][b=64][e=8] ----
__global__ __launch_bounds__(256) void init_state(const float* __restrict__ h0,
                                                  short* __restrict__ hhi,
                                                  short* __restrict__ hlo,
                                                  unsigned* __restrict__ bar) {
  int i = blockIdx.x * 256 + threadIdx.x;  // 0..65535 [l][b][j]
  int l = i >> 15, bj = i & 32767;
  int b = bj >> 9, j = bj & 511;
  float h = h0[i];
  short hi = f2bf(h);
  int o = (l * 2) * 32768 + (j >> 3) * 512 + b * 8 + (j & 7);
  hhi[o] = hi;
  hlo[o] = f2bf(h - bf2f(hi));
  if (i == 0) *bar = 0u;
}

// ---- lightweight grid barrier (all 128 blocks arrive every phase) ----
__device__ __forceinline__ void gbar(unsigned* bar, unsigned target, int tid) {
  __syncthreads();  // drains each wave's stores to L2 (vmcnt(0) before s_barrier)
  if (tid == 0) {
    __hip_atomic_fetch_add(bar, 1u, __ATOMIC_RELEASE, __HIP_MEMORY_SCOPE_AGENT);
    while (__hip_atomic_load(bar, __ATOMIC_RELAXED, __HIP_MEMORY_SCOPE_AGENT) <
           target)
      __builtin_amdgcn_s_sleep(1);
  }
  __syncthreads();
  __builtin_amdgcn_fence(__ATOMIC_ACQUIRE, "agent");  // L1+L2 invalidate
}

// ---- persistent LSTM ----------------------------------------------------
// grid 128 = [layer(2)][j8(64)]; block 512 = 8 waves (kq = wv&3, ah = wv>>2).
// dyn LDS 132096B: [0,98304) W image; [98304,..) float sG[4][32][66].
__global__ __launch_bounds__(512, 1) void lstm_persist(
    const short* __restrict__ wp, const float* __restrict__ x,
    const float* __restrict__ c0, const float* __restrict__ bih,
    const float* __restrict__ bhh, short* __restrict__ hhi,
    short* __restrict__ hlo, unsigned* __restrict__ bar,
    float* __restrict__ out) {
  extern __shared__ char smem[];
  short* lw = (short*)smem;             // 49152 shorts
  float* sG = (float*)(smem + 98304);   // [kq][s][b] stride 66

  const int tid = threadIdx.x;
  const int layer = blockIdx.x >> 6;
  const int j8 = blockIdx.x & 63;
  const int wv = tid >> 6;
  const int kq = wv & 3;                // K-quarter
  const int ah = wv >> 2;               // batch half
  const int lane = tid & 63;
  const int m = lane & 15;
  const int koq = lane >> 4;
  const int cbase = kq << 2;

  {  // W slice -> LDS (one-time)
    const short* src = wp + (size_t)(layer * 64 + j8) * 49152;
    for (int i = tid; i < 6144; i += 512)
      *(short8*)(lw + i * 8) = *(const short8*)(src + i * 8);
  }

  // per-thread cell: b = tid>>3, jj = tid&7  (h store offset = j8*512 + tid)
  const int sb = tid >> 3, sj = tid & 7;
  const int j = (j8 << 3) + sj;
  float creg = c0[layer * 32768 + sb * 512 + j];
  float hf = 0.f;
  float bsum[4];
#pragma unroll
  for (int g = 0; g < 4; ++g)
    bsum[g] = bih[layer * 2048 + g * 512 + j] + bhh[layer * 2048 + g * 512 + j];
  __syncthreads();

  for (int t = 0; t <= TT; ++t) {
    const int tl = layer ? (t - 1) : t;
    if (tl >= 0 && tl < TT) {
      const int pin = tl & 1, pout = pin ^ 1;
      f32x4 acc[2][2] = {};  // [j-tile][it]

      // ---- s=0: ih (single bf16) ----
      if (layer == 0) {
#pragma unroll
        for (int cc = 0; cc < 4; ++cc) {
          const int c = cbase + cc;
          const int k = c * 32 + (koq << 3);
          short8 b0 = *(const short8*)(lw + c * 512 + lane * 8);
          short8 b1 = *(const short8*)(lw + (16 + c) * 512 + lane * 8);
#pragma unroll
          for (int it = 0; it < 2; ++it) {
            const int br = ((ah * 2 + it) << 4) + m;
            const float* xp = x + ((size_t)br * TT + tl) * 512 + k;
            float4 u0 = *(const float4*)(xp);
            float4 u1 = *(const float4*)(xp + 4);
            short8 a;
            a[0] = f2bf(u0.x); a[1] = f2bf(u0.y); a[2] = f2bf(u0.z); a[3] = f2bf(u0.w);
            a[4] = f2bf(u1.x); a[5] = f2bf(u1.y); a[6] = f2bf(u1.z); a[7] = f2bf(u1.w);
            acc[0][it] = __builtin_amdgcn_mfma_f32_16x16x32_bf16(a, b0, acc[0][it], 0, 0, 0);
            acc[1][it] = __builtin_amdgcn_mfma_f32_16x16x32_bf16(a, b1, acc[1][it], 0, 0, 0);
          }
        }
      } else {
        const short* ah0 = hhi + (t & 1) * 32768;  // layer0 h(tl)
#pragma unroll
        for (int cc = 0; cc < 4; ++cc) {
          const int c = cbase + cc;
          const int cb = (c * 4 + koq) * 512;
          short8 b0 = *(const short8*)(lw + c * 512 + lane * 8);
          short8 b1 = *(const short8*)(lw + (16 + c) * 512 + lane * 8);
#pragma unroll
          for (int it = 0; it < 2; ++it) {
            const int br = ((ah * 2 + it) << 4) + m;
            short8 a = *(const short8*)(ah0 + cb + br * 8);
            acc[0][it] = __builtin_amdgcn_mfma_f32_16x16x32_bf16(a, b0, acc[0][it], 0, 0, 0);
            acc[1][it] = __builtin_amdgcn_mfma_f32_16x16x32_bf16(a, b1, acc[1][it], 0, 0, 0);
          }
        }
      }

      // ---- s=1: hh (hi+lo W x hi+lo h, 3 MFMA) ----
      {
        const short* rh = hhi + (layer * 2 + pin) * 32768;
        const short* rl = hlo + (layer * 2 + pin) * 32768;
#pragma unroll
        for (int cc = 0; cc < 4; ++cc) {
          const int c = cbase + cc;
          const int cb = (c * 4 + koq) * 512;
          short8 bh0 = *(const short8*)(lw + 16384 + (c * 2 + 0) * 512 + lane * 8);
          short8 bl0 = *(const short8*)(lw + 16384 + (c * 2 + 1) * 512 + lane * 8);
          short8 bh1 = *(const short8*)(lw + 16384 + ((16 + c) * 2 + 0) * 512 + lane * 8);
          short8 bl1 = *(const short8*)(lw + 16384 + ((16 + c) * 2 + 1) * 512 + lane * 8);
#pragma unroll
          for (int it = 0; it < 2; ++it) {
            const int br = ((ah * 2 + it) << 4) + m;
            short8 a = *(const short8*)(rh + cb + br * 8);
            short8 al = *(const short8*)(rl + cb + br * 8);
            acc[0][it] = __builtin_amdgcn_mfma_f32_16x16x32_bf16(a, bh0, acc[0][it], 0, 0, 0);
            acc[0][it] = __builtin_amdgcn_mfma_f32_16x16x32_bf16(a, bl0, acc[0][it], 0, 0, 0);
            acc[0][it] = __builtin_amdgcn_mfma_f32_16x16x32_bf16(al, bh0, acc[0][it], 0, 0, 0);
            acc[1][it] = __builtin_amdgcn_mfma_f32_16x16x32_bf16(a, bh1, acc[1][it], 0, 0, 0);
            acc[1][it] = __builtin_amdgcn_mfma_f32_16x16x32_bf16(a, bl1, acc[1][it], 0, 0, 0);
            acc[1][it] = __builtin_amdgcn_mfma_f32_16x16x32_bf16(al, bh1, acc[1][it], 0, 0, 0);
          }
        }
      }

      // ---- partials -> sG ----
#pragma unroll
      for (int bt = 0; bt < 2; ++bt)
#pragma unroll
        for (int it = 0; it < 2; ++it) {
          const int srow = bt * 16 + m;
          const int col = ((ah * 2 + it) << 4) + (koq << 2);
#pragma unroll
          for (int r = 0; r < 4; ++r)
            sG[(kq * 32 + srow) * 66 + col + r] = acc[bt][it][r];
        }
      __syncthreads();

      // ---- reduce + cell update (1 (b,j) pair/thread) ----
      {
        const int bt = sj >> 2, jl = sj & 3;
        float gv[4];
#pragma unroll
        for (int g = 0; g < 4; ++g) {
          const int s = bt * 16 + g * 4 + jl;
          gv[g] = sG[(0 * 32 + s) * 66 + sb] + sG[(1 * 32 + s) * 66 + sb] +
                  sG[(2 * 32 + s) * 66 + sb] + sG[(3 * 32 + s) * 66 + sb] +
                  bsum[g];
        }
        const float cn = sigf(gv[1]) * creg + sigf(gv[0]) * tanh_(gv[2]);
        const float hn = sigf(gv[3]) * tanh_(cn);
        creg = cn;
        hf = hn;
        const int ho = (layer * 2 + pout) * 32768 + j8 * 512 + tid;
        const short hb = f2bf(hn);
        hhi[ho] = hb;
        hlo[ho] = f2bf(hn - bf2f(hb));
        if (layer)
          __builtin_nontemporal_store(hn, &out[((size_t)sb * 512 + tl) * 512 + j]);
      }
    }
    if (t < TT) gbar(bar, (unsigned)(128 * (t + 1)), tid);
  }

  // finals from registers
  out[16777216 + layer * 32768 + sb * 512 + j] = hf;
  out[16777216 + 65536 + layer * 32768 + sb * 512 + j] = creg;
}

// ---- host ---------------------------------------------------------------

extern "C" void kernel_launch(void* const* d_in, const int* in_sizes, int n_in,
                              void* d_out, int out_size, void* d_ws,
                              size_t ws_size, hipStream_t stream) {
  const float* x = (const float*)d_in[0];
  const float* h0 = (const float*)d_in[1];
  const float* c0 = (const float*)d_in[2];
  const float* Wih = (const float*)d_in[3];
  const float* Whh = (const float*)d_in[4];
  const float* bih = (const float*)d_in[5];
  const float* bhh = (const float*)d_in[6];
  float* out = (float*)d_out;

  char* ws = (char*)d_ws;
  short* wp = (short*)(ws + 0);            // 12 MB  fragment-packed W images
  short* hhi = (short*)(ws + 12582912);    // 256 KB h hi [4 slots][k8][b][8]
  short* hlo = (short*)(ws + 12845056);    // 256 KB h lo
  unsigned* bar = (unsigned*)(ws + 13107200);  // barrier counter
  // total ws use: ~12.6 MB

  hipFuncSetAttribute(reinterpret_cast<const void*>(lstm_persist),
                      hipFuncAttributeMaxDynamicSharedMemorySize, 132096);

  conv_w<<<3072, 256, 0, stream>>>(Wih, Whh, wp);
  init_state<<<256, 256, 0, stream>>>(h0, hhi, hlo, bar);

  void* args[] = {(void*)&wp,  (void*)&x,   (void*)&c0, (void*)&bih,
                  (void*)&bhh, (void*)&hhi, (void*)&hlo, (void*)&bar,
                  (void*)&out};
  hipLaunchCooperativeKernel(reinterpret_cast<void*>(lstm_persist), dim3(128),
                             dim3(512), args, 132096, stream);
}

// Round 5
// 4882.694 us; speedup vs baseline: 3.7406x; 2.1088x over previous
//
#include <hip/hip_runtime.h>
#include <hip/hip_bf16.h>

// LSTM decoder: L=2, B=64, T=512, H=IN=512, gates G=2048 (i,f,g,o).
// Round 5: persistent kernel with FENCE-FREE grid barrier. All cross-block
// mutable data (h hi/lo) moves via explicitly-coherent ops (sc0 sc1 loads/
// stores bypassing L1/L2 to the device coherence point), so the barrier is
// just 8 padded relaxed agent atomics + relaxed polling -- no L2 writeback,
// no L2 invalidate. x/W/bias stay cached in L2 across all 512 steps.
// 128 blocks x 512 thr (8 waves: K-quarter x batch-half), W slice (96KB) in
// LDS, blocked h layout [slot][k8][b][8]. Numerics = validated rounds 2-4:
// ih single bf16 (x converted on the fly), hh = hi+lo W x hi+lo h.

#define TT 512

using short8 = __attribute__((ext_vector_type(8))) short;
using f32x4  = __attribute__((ext_vector_type(4))) float;

__device__ __forceinline__ short f2bf(float f) {
  unsigned u = __float_as_uint(f);
  u = (u + 0x7fffu + ((u >> 16) & 1u)) >> 16;  // RNE
  return (short)u;
}
__device__ __forceinline__ float bf2f(short s) {
  return __uint_as_float(((unsigned)(unsigned short)s) << 16);
}
__device__ __forceinline__ float sigf(float x) { return 1.f / (1.f + __expf(-x)); }
__device__ __forceinline__ float tanh_(float x) { return 1.f - 2.f / (__expf(2.f * x) + 1.f); }

// 8 coherent 16B loads (bypass L1+L2, read device coherence point), one wait.
__device__ __forceinline__ void ldc8(short8* d,
    const short* p0, const short* p1, const short* p2, const short* p3,
    const short* p4, const short* p5, const short* p6, const short* p7) {
  asm volatile(
      "global_load_dwordx4 %0, %8, off sc0 sc1\n\t"
      "global_load_dwordx4 %1, %9, off sc0 sc1\n\t"
      "global_load_dwordx4 %2, %10, off sc0 sc1\n\t"
      "global_load_dwordx4 %3, %11, off sc0 sc1\n\t"
      "global_load_dwordx4 %4, %12, off sc0 sc1\n\t"
      "global_load_dwordx4 %5, %13, off sc0 sc1\n\t"
      "global_load_dwordx4 %6, %14, off sc0 sc1\n\t"
      "global_load_dwordx4 %7, %15, off sc0 sc1\n\t"
      "s_waitcnt vmcnt(0)"
      : "=&v"(d[0]), "=&v"(d[1]), "=&v"(d[2]), "=&v"(d[3]),
        "=&v"(d[4]), "=&v"(d[5]), "=&v"(d[6]), "=&v"(d[7])
      : "v"(p0), "v"(p1), "v"(p2), "v"(p3),
        "v"(p4), "v"(p5), "v"(p6), "v"(p7)
      : "memory");
}

// coherent 2B store (write-through to device coherence point)
__device__ __forceinline__ void stc_short(short* p, short v) {
  asm volatile("global_store_short %0, %1, off sc0 sc1"
               :: "v"(p), "v"((int)v) : "memory");
}

// ---- W pack: per-block contiguous LDS image (49152 shorts per (l,j8)) ----
__global__ __launch_bounds__(256) void conv_w(const float* __restrict__ Wih,
                                              const float* __restrict__ Whh,
                                              short* __restrict__ wp) {
  int g = blockIdx.x * 256 + threadIdx.x;  // 0..786431
  int l = g / 393216;
  int rem = g % 393216;
  int j8 = rem / 6144;
  int q8 = rem % 6144;
  int s, hl, bt, c, lane;
  if (q8 < 2048) {
    s = 0; hl = 0;
    int seg = q8 >> 6; bt = seg >> 4; c = seg & 15; lane = q8 & 63;
  } else {
    int q = q8 - 2048;
    s = 1;
    int seg = q >> 6; bt = seg >> 5; c = (seg >> 1) & 15; hl = seg & 1;
    lane = q & 63;
  }
  int r = lane & 15;
  int gg = r >> 2, jj = r & 3;
  int R = gg * 512 + j8 * 8 + bt * 4 + jj;
  int k = c * 32 + (lane >> 4) * 8;
  const float* src = (s ? Whh : Wih) + ((size_t)(l * 2048 + R)) * 512 + k;
  short8 o;
#pragma unroll
  for (int e = 0; e < 8; ++e) {
    float v = src[e];
    short hi = f2bf(v);
    o[e] = hl ? f2bf(v - bf2f(hi)) : hi;
  }
  *(short8*)(wp + (size_t)g * 8) = o;
}

// ---- h0 -> parity-0 slots, blocked layout [slot][k8=64][b=64][e=8] ----
__global__ __launch_bounds__(256) void init_state(const float* __restrict__ h0,
                                                  short* __restrict__ hhi,
                                                  short* __restrict__ hlo,
                                                  unsigned* __restrict__ bar) {
  int i = blockIdx.x * 256 + threadIdx.x;  // 0..65535 [l][b][j]
  int l = i >> 15, bj = i & 32767;
  int b = bj >> 9, j = bj & 511;
  float h = h0[i];
  short hi = f2bf(h);
  int o = (l * 2) * 32768 + (j >> 3) * 512 + b * 8 + (j & 7);
  hhi[o] = hi;
  hlo[o] = f2bf(h - bf2f(hi));
  if (blockIdx.x == 0 && threadIdx.x < 256) bar[threadIdx.x] = 0u;
}

// ---- fence-free grid barrier: 8 padded counters, relaxed atomics ----
__device__ __forceinline__ void gbar(unsigned* bar, unsigned target, int tid,
                                     int slot) {
  __syncthreads();  // per-wave s_waitcnt vmcnt(0): coherent h stores drained
  if (tid == 0) {
    __hip_atomic_fetch_add(&bar[slot * 32], 1u, __ATOMIC_RELAXED,
                           __HIP_MEMORY_SCOPE_AGENT);
    for (;;) {
      unsigned sum = 0;
#pragma unroll
      for (int r = 0; r < 8; ++r)
        sum += __hip_atomic_load(&bar[r * 32], __ATOMIC_RELAXED,
                                 __HIP_MEMORY_SCOPE_AGENT);
      if (sum >= target) break;
      __builtin_amdgcn_s_sleep(2);
    }
  }
  __syncthreads();
}

// ---- persistent LSTM ----------------------------------------------------
// grid 128 = [layer(2)][j8(64)]; block 512 = 8 waves (kq = wv&3, ah = wv>>2).
// dyn LDS 132096B: [0,98304) W image; [98304,..) float sG[4][32][66].
__global__ __launch_bounds__(512, 1) void lstm_persist(
    const short* __restrict__ wp, const float* __restrict__ x,
    const float* __restrict__ c0, const float* __restrict__ bih,
    const float* __restrict__ bhh, short* __restrict__ hhi,
    short* __restrict__ hlo, unsigned* __restrict__ bar,
    float* __restrict__ out) {
  extern __shared__ char smem[];
  short* lw = (short*)smem;             // 49152 shorts
  float* sG = (float*)(smem + 98304);   // [kq][s][b] stride 66

  const int tid = threadIdx.x;
  const int layer = blockIdx.x >> 6;
  const int j8 = blockIdx.x & 63;
  const int bslot = blockIdx.x & 7;
  const int wv = tid >> 6;
  const int kq = wv & 3;                // K-quarter
  const int ah = wv >> 2;               // batch half
  const int lane = tid & 63;
  const int m = lane & 15;
  const int koq = lane >> 4;
  const int cbase = kq << 2;

  {  // W slice -> LDS (one-time)
    const short* src = wp + (size_t)(layer * 64 + j8) * 49152;
    for (int i = tid; i < 6144; i += 512)
      *(short8*)(lw + i * 8) = *(const short8*)(src + i * 8);
  }

  // per-thread cell: b = tid>>3, jj = tid&7
  const int sb = tid >> 3, sj = tid & 7;
  const int j = (j8 << 3) + sj;
  float creg = c0[layer * 32768 + sb * 512 + j];
  float hf = 0.f;
  float bsum[4];
#pragma unroll
  for (int g = 0; g < 4; ++g)
    bsum[g] = bih[layer * 2048 + g * 512 + j] + bhh[layer * 2048 + g * 512 + j];
  __syncthreads();

  const int br0 = ((ah * 2 + 0) << 4) + m;
  const int br1 = ((ah * 2 + 1) << 4) + m;

  for (int t = 0; t <= TT; ++t) {
    const int tl = layer ? (t - 1) : t;
    if (tl >= 0 && tl < TT) {
      const int pin = tl & 1, pout = pin ^ 1;
      f32x4 acc[2][2] = {};  // [j-tile][it]

#define PA(rX, cc, br) \
  ((rX) + ((((cbase + (cc)) << 2) + koq) << 9) + (br) * 8)

      // ---- coherent preload of recurrent a-fragments (hi+lo) ----
      short8 Ah[8], Al[8];
      {
        const short* rh = hhi + (layer * 2 + pin) * 32768;
        const short* rl = hlo + (layer * 2 + pin) * 32768;
        ldc8(Ah, PA(rh, 0, br0), PA(rh, 0, br1), PA(rh, 1, br0), PA(rh, 1, br1),
                 PA(rh, 2, br0), PA(rh, 2, br1), PA(rh, 3, br0), PA(rh, 3, br1));
        ldc8(Al, PA(rl, 0, br0), PA(rl, 0, br1), PA(rl, 1, br0), PA(rl, 1, br1),
                 PA(rl, 2, br0), PA(rl, 2, br1), PA(rl, 3, br0), PA(rl, 3, br1));
      }

      // ---- s=0: ih (single bf16) ----
      if (layer == 0) {
#pragma unroll
        for (int cc = 0; cc < 4; ++cc) {
          const int c = cbase + cc;
          const int k = c * 32 + (koq << 3);
          short8 b0 = *(const short8*)(lw + c * 512 + lane * 8);
          short8 b1 = *(const short8*)(lw + (16 + c) * 512 + lane * 8);
#pragma unroll
          for (int it = 0; it < 2; ++it) {
            const int br = it ? br1 : br0;
            const float* xp = x + ((size_t)br * TT + tl) * 512 + k;
            float4 u0 = *(const float4*)(xp);
            float4 u1 = *(const float4*)(xp + 4);
            short8 a;
            a[0] = f2bf(u0.x); a[1] = f2bf(u0.y); a[2] = f2bf(u0.z); a[3] = f2bf(u0.w);
            a[4] = f2bf(u1.x); a[5] = f2bf(u1.y); a[6] = f2bf(u1.z); a[7] = f2bf(u1.w);
            acc[0][it] = __builtin_amdgcn_mfma_f32_16x16x32_bf16(a, b0, acc[0][it], 0, 0, 0);
            acc[1][it] = __builtin_amdgcn_mfma_f32_16x16x32_bf16(a, b1, acc[1][it], 0, 0, 0);
          }
        }
      } else {
        short8 Ax[8];
        const short* ph = hhi + (t & 1) * 32768;  // layer0 h(tl)
        ldc8(Ax, PA(ph, 0, br0), PA(ph, 0, br1), PA(ph, 1, br0), PA(ph, 1, br1),
                 PA(ph, 2, br0), PA(ph, 2, br1), PA(ph, 3, br0), PA(ph, 3, br1));
#pragma unroll
        for (int cc = 0; cc < 4; ++cc) {
          const int c = cbase + cc;
          short8 b0 = *(const short8*)(lw + c * 512 + lane * 8);
          short8 b1 = *(const short8*)(lw + (16 + c) * 512 + lane * 8);
#pragma unroll
          for (int it = 0; it < 2; ++it) {
            short8 a = Ax[cc * 2 + it];
            acc[0][it] = __builtin_amdgcn_mfma_f32_16x16x32_bf16(a, b0, acc[0][it], 0, 0, 0);
            acc[1][it] = __builtin_amdgcn_mfma_f32_16x16x32_bf16(a, b1, acc[1][it], 0, 0, 0);
          }
        }
      }

      // ---- s=1: hh (hi+lo W x hi+lo h, 3 MFMA) ----
#pragma unroll
      for (int cc = 0; cc < 4; ++cc) {
        const int c = cbase + cc;
        short8 bh0 = *(const short8*)(lw + 16384 + (c * 2 + 0) * 512 + lane * 8);
        short8 bl0 = *(const short8*)(lw + 16384 + (c * 2 + 1) * 512 + lane * 8);
        short8 bh1 = *(const short8*)(lw + 16384 + ((16 + c) * 2 + 0) * 512 + lane * 8);
        short8 bl1 = *(const short8*)(lw + 16384 + ((16 + c) * 2 + 1) * 512 + lane * 8);
#pragma unroll
        for (int it = 0; it < 2; ++it) {
          short8 a = Ah[cc * 2 + it];
          short8 al = Al[cc * 2 + it];
          acc[0][it] = __builtin_amdgcn_mfma_f32_16x16x32_bf16(a, bh0, acc[0][it], 0, 0, 0);
          acc[0][it] = __builtin_amdgcn_mfma_f32_16x16x32_bf16(a, bl0, acc[0][it], 0, 0, 0);
          acc[0][it] = __builtin_amdgcn_mfma_f32_16x16x32_bf16(al, bh0, acc[0][it], 0, 0, 0);
          acc[1][it] = __builtin_amdgcn_mfma_f32_16x16x32_bf16(a, bh1, acc[1][it], 0, 0, 0);
          acc[1][it] = __builtin_amdgcn_mfma_f32_16x16x32_bf16(a, bl1, acc[1][it], 0, 0, 0);
          acc[1][it] = __builtin_amdgcn_mfma_f32_16x16x32_bf16(al, bh1, acc[1][it], 0, 0, 0);
        }
      }

      // ---- partials -> sG ----
#pragma unroll
      for (int bt = 0; bt < 2; ++bt)
#pragma unroll
        for (int it = 0; it < 2; ++it) {
          const int srow = bt * 16 + m;
          const int col = ((ah * 2 + it) << 4) + (koq << 2);
#pragma unroll
          for (int r = 0; r < 4; ++r)
            sG[(kq * 32 + srow) * 66 + col + r] = acc[bt][it][r];
        }
      __syncthreads();

      // ---- reduce + cell update (1 (b,j) pair/thread) ----
      {
        const int bt = sj >> 2, jl = sj & 3;
        float gv[4];
#pragma unroll
        for (int g = 0; g < 4; ++g) {
          const int s = bt * 16 + g * 4 + jl;
          gv[g] = sG[(0 * 32 + s) * 66 + sb] + sG[(1 * 32 + s) * 66 + sb] +
                  sG[(2 * 32 + s) * 66 + sb] + sG[(3 * 32 + s) * 66 + sb] +
                  bsum[g];
        }
        const float cn = sigf(gv[1]) * creg + sigf(gv[0]) * tanh_(gv[2]);
        const float hn = sigf(gv[3]) * tanh_(cn);
        creg = cn;
        hf = hn;
        const int ho = (layer * 2 + pout) * 32768 + (j8 << 9) + tid;
        const short hb = f2bf(hn);
        stc_short(hhi + ho, hb);
        stc_short(hlo + ho, f2bf(hn - bf2f(hb)));
        if (layer)
          __builtin_nontemporal_store(hn, &out[((size_t)sb * 512 + tl) * 512 + j]);
      }
    }
    if (t < TT) gbar(bar, (unsigned)(128 * (t + 1)), tid, bslot);
  }

  // finals from registers (end-of-kernel release makes them visible)
  out[16777216 + layer * 32768 + sb * 512 + j] = hf;
  out[16777216 + 65536 + layer * 32768 + sb * 512 + j] = creg;
}

// ---- host ---------------------------------------------------------------

extern "C" void kernel_launch(void* const* d_in, const int* in_sizes, int n_in,
                              void* d_out, int out_size, void* d_ws,
                              size_t ws_size, hipStream_t stream) {
  const float* x = (const float*)d_in[0];
  const float* h0 = (const float*)d_in[1];
  const float* c0 = (const float*)d_in[2];
  const float* Wih = (const float*)d_in[3];
  const float* Whh = (const float*)d_in[4];
  const float* bih = (const float*)d_in[5];
  const float* bhh = (const float*)d_in[6];
  float* out = (float*)d_out;

  char* ws = (char*)d_ws;
  short* wp = (short*)(ws + 0);            // 12 MB  fragment-packed W images
  short* hhi = (short*)(ws + 12582912);    // 256 KB h hi [4 slots][k8][b][8]
  short* hlo = (short*)(ws + 12845056);    // 256 KB h lo
  unsigned* bar = (unsigned*)(ws + 13107200);  // 1 KB: 8 padded counters
  // total ws use: ~12.6 MB

  hipFuncSetAttribute(reinterpret_cast<const void*>(lstm_persist),
                      hipFuncAttributeMaxDynamicSharedMemorySize, 132096);

  conv_w<<<3072, 256, 0, stream>>>(Wih, Whh, wp);
  init_state<<<256, 256, 0, stream>>>(h0, hhi, hlo, bar);

  void* args[] = {(void*)&wp,  (void*)&x,   (void*)&c0,  (void*)&bih,
                  (void*)&bhh, (void*)&hhi, (void*)&hlo, (void*)&bar,
                  (void*)&out};
  hipLaunchCooperativeKernel(reinterpret_cast<void*>(lstm_persist), dim3(128),
                             dim3(512), args, 132096, stream);
}

// Round 6
// 2734.711 us; speedup vs baseline: 6.6786x; 1.7855x over previous
//
#include <hip/hip_runtime.h>
#include <hip/hip_bf16.h>

// LSTM decoder: L=2, B=64, T=512, H=IN=512, gates G=2048 (i,f,g,o).
// Round 6: latency-engineered persistent kernel.
//  - split-phase fence-free barrier (arrive early / wait late), 32 padded
//    counters, relaxed agent atomics (no L2 flush/inv -- round-5 proven)
//  - ALL coherent h loads issued in one burst; tied s_waitcnt vmcnt(16)
//    starts layer-1 ih while hh operands are still in flight; vmcnt(0)
//    before hh. One MALL round-trip per step instead of three.
//  - layer-0 ih(t+1) computed AFTER arrival (overlaps other blocks' wait);
//    x pre-converted to bf16 into d_out rows (row (b,t) consumed at phase t,
//    overwritten by layer-1 at phase t+1 -- barrier-ordered, round-3 proven).
// Numerics = validated rounds 2-5: ih single bf16, hh hi+lo W x hi+lo h.

#define TT 512

using short8 = __attribute__((ext_vector_type(8))) short;
using f32x4  = __attribute__((ext_vector_type(4))) float;

__device__ __forceinline__ short f2bf(float f) {
  unsigned u = __float_as_uint(f);
  u = (u + 0x7fffu + ((u >> 16) & 1u)) >> 16;  // RNE
  return (short)u;
}
__device__ __forceinline__ float bf2f(short s) {
  return __uint_as_float(((unsigned)(unsigned short)s) << 16);
}
__device__ __forceinline__ float sigf(float x) { return 1.f / (1.f + __expf(-x)); }
__device__ __forceinline__ float tanh_(float x) { return 1.f - 2.f / (__expf(2.f * x) + 1.f); }

// 8 coherent 16B loads, NO wait (caller ties the waitcnt to the results).
__device__ __forceinline__ void ld8_nw(short8* d,
    const short* p0, const short* p1, const short* p2, const short* p3,
    const short* p4, const short* p5, const short* p6, const short* p7) {
  asm volatile(
      "global_load_dwordx4 %0, %8, off sc0 sc1\n\t"
      "global_load_dwordx4 %1, %9, off sc0 sc1\n\t"
      "global_load_dwordx4 %2, %10, off sc0 sc1\n\t"
      "global_load_dwordx4 %3, %11, off sc0 sc1\n\t"
      "global_load_dwordx4 %4, %12, off sc0 sc1\n\t"
      "global_load_dwordx4 %5, %13, off sc0 sc1\n\t"
      "global_load_dwordx4 %6, %14, off sc0 sc1\n\t"
      "global_load_dwordx4 %7, %15, off sc0 sc1"
      : "=&v"(d[0]), "=&v"(d[1]), "=&v"(d[2]), "=&v"(d[3]),
        "=&v"(d[4]), "=&v"(d[5]), "=&v"(d[6]), "=&v"(d[7])
      : "v"(p0), "v"(p1), "v"(p2), "v"(p3),
        "v"(p4), "v"(p5), "v"(p6), "v"(p7)
      : "memory");
}

// tie a waitcnt (or nothing) to 8 loaded fragments so no use precedes it
#define TIE8(A, CNT)                                                        \
  asm volatile(CNT : "+v"(A[0]), "+v"(A[1]), "+v"(A[2]), "+v"(A[3]),        \
                     "+v"(A[4]), "+v"(A[5]), "+v"(A[6]), "+v"(A[7])         \
               ::"memory")

// coherent 2B store (write-through to device coherence point)
__device__ __forceinline__ void stc_short(short* p, short v) {
  asm volatile("global_store_short %0, %1, off sc0 sc1"
               :: "v"(p), "v"((int)v) : "memory");
}

// ---- x fp32 [64][512][512] -> bf16 in first half of each out row ----
__global__ __launch_bounds__(256) void conv_x(const float* __restrict__ x,
                                              short* __restrict__ xo) {
  size_t g = (size_t)blockIdx.x * 256 + threadIdx.x;  // 2,097,152
  size_t i = g * 8;
  float4 v0 = *(const float4*)(x + i);
  float4 v1 = *(const float4*)(x + i + 4);
  short8 r;
  r[0] = f2bf(v0.x); r[1] = f2bf(v0.y); r[2] = f2bf(v0.z); r[3] = f2bf(v0.w);
  r[4] = f2bf(v1.x); r[5] = f2bf(v1.y); r[6] = f2bf(v1.z); r[7] = f2bf(v1.w);
  *(short8*)(xo + (i >> 9) * 1024 + (i & 511)) = r;
}

// ---- W pack: per-block contiguous LDS image (49152 shorts per (l,j8)) ----
__global__ __launch_bounds__(256) void conv_w(const float* __restrict__ Wih,
                                              const float* __restrict__ Whh,
                                              short* __restrict__ wp) {
  int g = blockIdx.x * 256 + threadIdx.x;  // 0..786431
  int l = g / 393216;
  int rem = g % 393216;
  int j8 = rem / 6144;
  int q8 = rem % 6144;
  int s, hl, bt, c, lane;
  if (q8 < 2048) {
    s = 0; hl = 0;
    int seg = q8 >> 6; bt = seg >> 4; c = seg & 15; lane = q8 & 63;
  } else {
    int q = q8 - 2048;
    s = 1;
    int seg = q >> 6; bt = seg >> 5; c = (seg >> 1) & 15; hl = seg & 1;
    lane = q & 63;
  }
  int r = lane & 15;
  int gg = r >> 2, jj = r & 3;
  int R = gg * 512 + j8 * 8 + bt * 4 + jj;
  int k = c * 32 + (lane >> 4) * 8;
  const float* src = (s ? Whh : Wih) + ((size_t)(l * 2048 + R)) * 512 + k;
  short8 o;
#pragma unroll
  for (int e = 0; e < 8; ++e) {
    float v = src[e];
    short hi = f2bf(v);
    o[e] = hl ? f2bf(v - bf2f(hi)) : hi;
  }
  *(short8*)(wp + (size_t)g * 8) = o;
}

// ---- h0 -> parity-0 slots, blocked layout [slot][k8=64][b=64][e=8] ----
__global__ __launch_bounds__(256) void init_state(const float* __restrict__ h0,
                                                  short* __restrict__ hhi,
                                                  short* __restrict__ hlo,
                                                  unsigned* __restrict__ bar) {
  int i = blockIdx.x * 256 + threadIdx.x;  // 0..65535 [l][b][j]
  int l = i >> 15, bj = i & 32767;
  int b = bj >> 9, j = bj & 511;
  float h = h0[i];
  short hi = f2bf(h);
  int o = (l * 2) * 32768 + (j >> 3) * 512 + b * 8 + (j & 7);
  hhi[o] = hi;
  hlo[o] = f2bf(h - bf2f(hi));
  if (blockIdx.x < 4) bar[blockIdx.x * 256 + threadIdx.x] = 0u;
}

// ---- split-phase fence-free grid barrier ----
__device__ __forceinline__ void garrive(unsigned* bar, int tid, int slot) {
  __syncthreads();  // drains coherent h stores (vmcnt(0) before s_barrier)
  if (tid == 0)
    __hip_atomic_fetch_add(&bar[slot * 32], 1u, __ATOMIC_RELAXED,
                           __HIP_MEMORY_SCOPE_AGENT);
}
__device__ __forceinline__ void gwait(unsigned* bar, unsigned target, int tid) {
  if (tid == 0) {
    for (;;) {
      unsigned sum = 0;
#pragma unroll
      for (int r = 0; r < 32; ++r)
        sum += __hip_atomic_load(&bar[r * 32], __ATOMIC_RELAXED,
                                 __HIP_MEMORY_SCOPE_AGENT);
      if (sum >= target) break;
      __builtin_amdgcn_s_sleep(1);
    }
  }
  __syncthreads();
}

// ---- persistent LSTM ----------------------------------------------------
// grid 128 = [layer(2)][j8(64)]; block 512 = 8 waves (kq = wv&3, ah = wv>>2).
// dyn LDS 132096B: [0,98304) W image; [98304,..) float sG[4][32][66].
__global__ __launch_bounds__(512, 1) void lstm_persist(
    const short* __restrict__ wp, const float* __restrict__ c0,
    const float* __restrict__ bih, const float* __restrict__ bhh,
    short* __restrict__ hhi, short* __restrict__ hlo,
    unsigned* __restrict__ bar, float* __restrict__ out) {
  extern __shared__ char smem[];
  short* lw = (short*)smem;             // 49152 shorts
  float* sG = (float*)(smem + 98304);   // [kq][s][b] stride 66

  const int tid = threadIdx.x;
  const int layer = blockIdx.x >> 6;
  const int j8 = blockIdx.x & 63;
  const int bslot = blockIdx.x & 31;
  const int wv = tid >> 6;
  const int kq = wv & 3;
  const int ah = wv >> 2;
  const int lane = tid & 63;
  const int m = lane & 15;
  const int koq = lane >> 4;
  const int cbase = kq << 2;

  {  // W slice -> LDS (one-time)
    const short* src = wp + (size_t)(layer * 64 + j8) * 49152;
    for (int i = tid; i < 6144; i += 512)
      *(short8*)(lw + i * 8) = *(const short8*)(src + i * 8);
  }

  const int sb = tid >> 3, sj = tid & 7;
  const int j = (j8 << 3) + sj;
  float creg = c0[layer * 32768 + sb * 512 + j];
  float hf = 0.f;
  float bsum[4];
#pragma unroll
  for (int g = 0; g < 4; ++g)
    bsum[g] = bih[layer * 2048 + g * 512 + j] + bhh[layer * 2048 + g * 512 + j];
  __syncthreads();

  const int br0 = ((ah * 2 + 0) << 4) + m;
  const int br1 = ((ah * 2 + 1) << 4) + m;
  const short* xo = (const short*)out;

  f32x4 acc[2][2];

  // layer-0 ih for a given timestep from bf16 x rows (B-frags from LDS)
  auto ih_l0 = [&](int txt) {
#pragma unroll
    for (int cc = 0; cc < 4; ++cc) {
      const int c = cbase + cc;
      const int k = c * 32 + (koq << 3);
      short8 b0 = *(const short8*)(lw + c * 512 + lane * 8);
      short8 b1 = *(const short8*)(lw + (16 + c) * 512 + lane * 8);
#pragma unroll
      for (int it = 0; it < 2; ++it) {
        const int br = it ? br1 : br0;
        short8 a = *(const short8*)(xo + ((size_t)br * TT + txt) * 1024 + k);
        acc[0][it] = __builtin_amdgcn_mfma_f32_16x16x32_bf16(a, b0, acc[0][it], 0, 0, 0);
        acc[1][it] = __builtin_amdgcn_mfma_f32_16x16x32_bf16(a, b1, acc[1][it], 0, 0, 0);
      }
    }
  };

  if (layer == 0) {
#pragma unroll
    for (int u = 0; u < 2; ++u)
#pragma unroll
      for (int v = 0; v < 2; ++v) acc[u][v] = f32x4{0.f, 0.f, 0.f, 0.f};
    ih_l0(0);  // prologue: ih(t=0)
  }

#define PA(rX, cc, br) \
  ((rX) + ((((cbase + (cc)) << 2) + koq) << 9) + (br) * 8)

  for (int t = 0; t <= TT; ++t) {
    const int tl = layer ? (t - 1) : t;
    if (tl >= 0 && tl < TT) {
      const int pin = tl & 1, pout = pin ^ 1;
      if (t > 0) gwait(bar, 128u * (unsigned)t, tid);

      short8 Ah[8], Al[8];
      const short* rh = hhi + (layer * 2 + pin) * 32768;
      const short* rl = hlo + (layer * 2 + pin) * 32768;

      if (layer == 0) {
        // acc holds ih(t) (computed post-arrival last phase). One trip for hh.
        ld8_nw(Ah, PA(rh, 0, br0), PA(rh, 0, br1), PA(rh, 1, br0), PA(rh, 1, br1),
                   PA(rh, 2, br0), PA(rh, 2, br1), PA(rh, 3, br0), PA(rh, 3, br1));
        ld8_nw(Al, PA(rl, 0, br0), PA(rl, 0, br1), PA(rl, 1, br0), PA(rl, 1, br1),
                   PA(rl, 2, br0), PA(rl, 2, br1), PA(rl, 3, br0), PA(rl, 3, br1));
        TIE8(Ah, "s_waitcnt vmcnt(0)");
        TIE8(Al, "");
      } else {
#pragma unroll
        for (int u = 0; u < 2; ++u)
#pragma unroll
          for (int v = 0; v < 2; ++v) acc[u][v] = f32x4{0.f, 0.f, 0.f, 0.f};
        short8 Ax[8];
        const short* ph = hhi + (t & 1) * 32768;  // layer0 h(tl)
        ld8_nw(Ax, PA(ph, 0, br0), PA(ph, 0, br1), PA(ph, 1, br0), PA(ph, 1, br1),
                   PA(ph, 2, br0), PA(ph, 2, br1), PA(ph, 3, br0), PA(ph, 3, br1));
        ld8_nw(Ah, PA(rh, 0, br0), PA(rh, 0, br1), PA(rh, 1, br0), PA(rh, 1, br1),
                   PA(rh, 2, br0), PA(rh, 2, br1), PA(rh, 3, br0), PA(rh, 3, br1));
        ld8_nw(Al, PA(rl, 0, br0), PA(rl, 0, br1), PA(rl, 1, br0), PA(rl, 1, br1),
                   PA(rl, 2, br0), PA(rl, 2, br1), PA(rl, 3, br0), PA(rl, 3, br1));
        TIE8(Ax, "s_waitcnt vmcnt(16)");  // Ax (oldest 8) done; Ah/Al in flight
#pragma unroll
        for (int cc = 0; cc < 4; ++cc) {
          const int c = cbase + cc;
          short8 b0 = *(const short8*)(lw + c * 512 + lane * 8);
          short8 b1 = *(const short8*)(lw + (16 + c) * 512 + lane * 8);
#pragma unroll
          for (int it = 0; it < 2; ++it) {
            short8 a = Ax[cc * 2 + it];
            acc[0][it] = __builtin_amdgcn_mfma_f32_16x16x32_bf16(a, b0, acc[0][it], 0, 0, 0);
            acc[1][it] = __builtin_amdgcn_mfma_f32_16x16x32_bf16(a, b1, acc[1][it], 0, 0, 0);
          }
        }
        TIE8(Ah, "s_waitcnt vmcnt(0)");
        TIE8(Al, "");
      }

      // ---- hh: hi+lo W x hi+lo h (3 MFMA) ----
#pragma unroll
      for (int cc = 0; cc < 4; ++cc) {
        const int c = cbase + cc;
        short8 bh0 = *(const short8*)(lw + 16384 + (c * 2 + 0) * 512 + lane * 8);
        short8 bl0 = *(const short8*)(lw + 16384 + (c * 2 + 1) * 512 + lane * 8);
        short8 bh1 = *(const short8*)(lw + 16384 + ((16 + c) * 2 + 0) * 512 + lane * 8);
        short8 bl1 = *(const short8*)(lw + 16384 + ((16 + c) * 2 + 1) * 512 + lane * 8);
#pragma unroll
        for (int it = 0; it < 2; ++it) {
          short8 a = Ah[cc * 2 + it];
          short8 al = Al[cc * 2 + it];
          acc[0][it] = __builtin_amdgcn_mfma_f32_16x16x32_bf16(a, bh0, acc[0][it], 0, 0, 0);
          acc[0][it] = __builtin_amdgcn_mfma_f32_16x16x32_bf16(a, bl0, acc[0][it], 0, 0, 0);
          acc[0][it] = __builtin_amdgcn_mfma_f32_16x16x32_bf16(al, bh0, acc[0][it], 0, 0, 0);
          acc[1][it] = __builtin_amdgcn_mfma_f32_16x16x32_bf16(a, bh1, acc[1][it], 0, 0, 0);
          acc[1][it] = __builtin_amdgcn_mfma_f32_16x16x32_bf16(a, bl1, acc[1][it], 0, 0, 0);
          acc[1][it] = __builtin_amdgcn_mfma_f32_16x16x32_bf16(al, bh1, acc[1][it], 0, 0, 0);
        }
      }

      // ---- partials -> sG ----
#pragma unroll
      for (int bt = 0; bt < 2; ++bt)
#pragma unroll
        for (int it = 0; it < 2; ++it) {
          const int srow = bt * 16 + m;
          const int col = ((ah * 2 + it) << 4) + (koq << 2);
#pragma unroll
          for (int r = 0; r < 4; ++r)
            sG[(kq * 32 + srow) * 66 + col + r] = acc[bt][it][r];
        }
      __syncthreads();

      // ---- reduce + cell update ----
      {
        const int bt = sj >> 2, jl = sj & 3;
        float gv[4];
#pragma unroll
        for (int g = 0; g < 4; ++g) {
          const int s = bt * 16 + g * 4 + jl;
          gv[g] = sG[(0 * 32 + s) * 66 + sb] + sG[(1 * 32 + s) * 66 + sb] +
                  sG[(2 * 32 + s) * 66 + sb] + sG[(3 * 32 + s) * 66 + sb] +
                  bsum[g];
        }
        const float cn = sigf(gv[1]) * creg + sigf(gv[0]) * tanh_(gv[2]);
        const float hn = sigf(gv[3]) * tanh_(cn);
        creg = cn;
        hf = hn;
        const int ho = (layer * 2 + pout) * 32768 + (j8 << 9) + tid;
        const short hb = f2bf(hn);
        stc_short(hhi + ho, hb);
        stc_short(hlo + ho, f2bf(hn - bf2f(hb)));
        if (layer)
          __builtin_nontemporal_store(hn, &out[((size_t)sb * 512 + tl) * 512 + j]);
      }
    }
    if (t < TT) {
      garrive(bar, tid, bslot);
      if (layer == 0 && t + 1 < TT) {  // overlap next ih with others' wait
#pragma unroll
        for (int u = 0; u < 2; ++u)
#pragma unroll
          for (int v = 0; v < 2; ++v) acc[u][v] = f32x4{0.f, 0.f, 0.f, 0.f};
        ih_l0(t + 1);
      }
    }
  }

  // finals from registers
  out[16777216 + layer * 32768 + sb * 512 + j] = hf;
  out[16777216 + 65536 + layer * 32768 + sb * 512 + j] = creg;
}

// ---- host ---------------------------------------------------------------

extern "C" void kernel_launch(void* const* d_in, const int* in_sizes, int n_in,
                              void* d_out, int out_size, void* d_ws,
                              size_t ws_size, hipStream_t stream) {
  const float* x = (const float*)d_in[0];
  const float* h0 = (const float*)d_in[1];
  const float* c0 = (const float*)d_in[2];
  const float* Wih = (const float*)d_in[3];
  const float* Whh = (const float*)d_in[4];
  const float* bih = (const float*)d_in[5];
  const float* bhh = (const float*)d_in[6];
  float* out = (float*)d_out;

  char* ws = (char*)d_ws;
  short* wp = (short*)(ws + 0);            // 12 MB  fragment-packed W images
  short* hhi = (short*)(ws + 12582912);    // 256 KB h hi [4 slots][k8][b][8]
  short* hlo = (short*)(ws + 12845056);    // 256 KB h lo
  unsigned* bar = (unsigned*)(ws + 13107200);  // 4 KB: 32 padded counters
  // total ws use: ~12.6 MB (round-2-proven budget)

  hipFuncSetAttribute(reinterpret_cast<const void*>(lstm_persist),
                      hipFuncAttributeMaxDynamicSharedMemorySize, 132096);

  conv_x<<<8192, 256, 0, stream>>>(x, (short*)out);
  conv_w<<<3072, 256, 0, stream>>>(Wih, Whh, wp);
  init_state<<<256, 256, 0, stream>>>(h0, hhi, hlo, bar);

  void* args[] = {(void*)&wp,  (void*)&c0,  (void*)&bih, (void*)&bhh,
                  (void*)&hhi, (void*)&hlo, (void*)&bar, (void*)&out};
  hipLaunchCooperativeKernel(reinterpret_cast<void*>(lstm_persist), dim3(128),
                             dim3(512), args, 132096, stream);
}